// Round 8
// baseline (1521.083 us; speedup 1.0000x reference)
//
#include <hip/hip_runtime.h>
#include <cstdint>
#include <cstddef>

// ---------------------------------------------------------------------------
// DockPointNet fused edge-MLP + segment-max, f16 MFMA + CSR counting sort.
// Round 8: swapped-operand GEMMs (D = W^T · msg^T) make LN reductions
// edge-local: lane (c16,g) holds channels j*16+4g+q of edge c16, so LN stats
// = in-lane adds + 2 proven __shfl_xor (xor16, xor32) instead of 64
// ds_swizzles; h1/h2 write-back packs 4 consecutive channels per frag into
// ds_write_b64 on the lane's own row. Weights in registers (A-frags).
// DS pipe per wave-tile: ~1200cy (r6) -> ~430cy. No DPP (r7's failure
// isolated to exotic primitives; this uses only r2-r6-proven pieces).
// ---------------------------------------------------------------------------

typedef _Float16 f16x8 __attribute__((ext_vector_type(8)));
typedef _Float16 f16x4 __attribute__((ext_vector_type(4)));
typedef _Float16 f16x2 __attribute__((ext_vector_type(2)));
typedef float    f32x4 __attribute__((ext_vector_type(4)));

#define ENC_NEGINF 0x007FFFFFu   // fenc(-inf)
#define LDK 64                   // msg row stride (f16); XOR swizzle on 8-blocks
#define LDH 132                  // h2 row stride (f16)

__device__ __forceinline__ int swz(int row, int col) {
    return (col & 7) | ((((col >> 3) ^ row) & 7) << 3);
}

__device__ __forceinline__ unsigned fenc(float f) {
    unsigned u = __float_as_uint(f);
    return (u & 0x80000000u) ? ~u : (u | 0x80000000u);
}

__global__ void init_out_kernel(unsigned* __restrict__ out, int n4) {
    int i = blockIdx.x * blockDim.x + threadIdx.x;
    if (i < n4)
        ((uint4*)out)[i] = make_uint4(ENC_NEGINF, ENC_NEGINF, ENC_NEGINF, ENC_NEGINF);
}

__global__ void finalize_out_kernel(float* __restrict__ out, int n) {
    int i = blockIdx.x * blockDim.x + threadIdx.x;
    if (i < n) {
        unsigned k = __float_as_uint(out[i]);
        float r;
        if (k == ENC_NEGINF) r = 0.0f;
        else {
            unsigned u = (k & 0x80000000u) ? (k ^ 0x80000000u) : ~k;
            r = __uint_as_float(u);
        }
        out[i] = r;
    }
}

// ---------------- CSR build (r6 verbatim) ----------------
__global__ void zero_kernel(int* __restrict__ p, int n) {
    int i = blockIdx.x * blockDim.x + threadIdx.x;
    if (i < n) p[i] = 0;
}

__global__ void hist_kernel(const int* __restrict__ dstI, int* __restrict__ counts, int E) {
    int i = blockIdx.x * blockDim.x + threadIdx.x;
    if (i < E) atomicAdd(&counts[dstI[i]], 1);
}

__global__ __launch_bounds__(1024) void scan_blk(const int* __restrict__ in,
                                                 int* __restrict__ outp,
                                                 int* __restrict__ bsums, int N) {
    __shared__ int wsum[16];
    const int tid = threadIdx.x, lane = tid & 63, wid = tid >> 6;
    int i = blockIdx.x * 1024 + tid;
    int v = (i < N) ? in[i] : 0;
    int incl = v;
#pragma unroll
    for (int m = 1; m < 64; m <<= 1) {
        int t = __shfl_up(incl, m, 64);
        if (lane >= m) incl += t;
    }
    if (lane == 63) wsum[wid] = incl;
    __syncthreads();
    int woff = 0;
#pragma unroll
    for (int k = 0; k < 16; ++k) woff += (k < wid) ? wsum[k] : 0;
    if (i < N) outp[i] = woff + incl - v;
    if (tid == 1023 && bsums != nullptr) bsums[blockIdx.x] = woff + incl;
}

__global__ __launch_bounds__(1024) void scan_add(int* __restrict__ outp,
                                                 const int* __restrict__ bsums, int N) {
    int i = blockIdx.x * 1024 + threadIdx.x;
    if (i < N) outp[i] += bsums[blockIdx.x];
}

__global__ void scatter_kernel(const int* __restrict__ srcI, const int* __restrict__ dstI,
                               int* __restrict__ nextp,
                               int2* __restrict__ se, int* __restrict__ dst_g, int E) {
    int i = blockIdx.x * blockDim.x + threadIdx.x;
    if (i < E) {
        int d = dstI[i];
        int p = atomicAdd(&nextp[d], 1);
        se[p] = make_int2(srcI[i], i);
        dst_g[p] = d;
    }
}

// ---------------- CSR edge kernel: swapped-operand GEMMs ----------------
__global__ __launch_bounds__(256, 2) void edge_kernel_csr(
    const float* __restrict__ x,   const float* __restrict__ pos,
    const float* __restrict__ nrm, const float* __restrict__ ea,
    const float* __restrict__ W1,  const float* __restrict__ b1,
    const float* __restrict__ g1,  const float* __restrict__ be1,
    const float* __restrict__ W2,  const float* __restrict__ b2,
    const float* __restrict__ g2,  const float* __restrict__ be2,
    const int2* __restrict__ se,   const int* __restrict__ dst_g,
    unsigned* __restrict__ out, int E, int ntiles)
{
    __shared__ _Float16 msgA[64][LDK];   // 8 KB  [edge][ch]; h1 aliased after GEMM1
    __shared__ _Float16 h2w[64][LDH];    // 16.5 KB [edge][out-ch] (r6 walk layout)
    __shared__ int dstL[64];

    const int lane = threadIdx.x & 63;
    const int w    = threadIdx.x >> 6;   // 0..3
    const int c16  = lane & 15;
    const int g    = lane >> 4;
    const int row0 = w * 16;

    // ---- weights as A-fragments in registers (tile-invariant).
    // A-frag layout (proven r2-r6, symmetric to B): lane (c16,g) holds
    // A[m = blk*16+c16][k = ks*32+g*8+i]. Row k==47 carries the bias
    // (msg/h1 col 47 is the constant 1.0).
    f16x8 w1a[3][2];
#pragma unroll
    for (int j = 0; j < 3; ++j) {
        int m = j * 16 + c16;
#pragma unroll
        for (int ks = 0; ks < 2; ++ks) {
            f16x8 v;
#pragma unroll
            for (int i = 0; i < 8; ++i) {
                int k = ks * 32 + g * 8 + i;
                float f = 0.f;
                if (m < 47) {
                    if (k < 47)       f = W1[k * 47 + m];
                    else if (k == 47) f = b1[m];
                }
                v[i] = (_Float16)f;
            }
            w1a[j][ks] = v;
        }
    }
    f16x8 w2a[8][2];
#pragma unroll
    for (int j = 0; j < 8; ++j) {
        int m = j * 16 + c16;
#pragma unroll
        for (int ks = 0; ks < 2; ++ks) {
            f16x8 v;
#pragma unroll
            for (int i = 0; i < 8; ++i) {
                int k = ks * 32 + g * 8 + i;
                float f = 0.f;
                if (k < 47)       f = W2[k * 128 + m];
                else if (k == 47) f = b2[m];
                v[i] = (_Float16)f;
            }
            w2a[j][ks] = v;
        }
    }

    // ---- LN params, per-lane channels ch = j*16 + 4g + q (f16-packed) ----
    f16x4 g1p[3], be1p[3];
#pragma unroll
    for (int j = 0; j < 3; ++j) {
#pragma unroll
        for (int q = 0; q < 4; ++q) {
            int cc = j * 16 + 4 * g + q;
            bool vld = cc < 47;
            g1p[j][q]  = (_Float16)(vld ? g1[cc]  : 0.f);
            be1p[j][q] = (_Float16)(vld ? be1[cc] : 0.f);
        }
    }
    f16x4 g2p[8], be2p[8];
#pragma unroll
    for (int j = 0; j < 8; ++j) {
#pragma unroll
        for (int q = 0; q < 4; ++q) {
            int cc = j * 16 + 4 * g + q;
            g2p[j][q]  = (_Float16)g2[cc];
            be2p[j][q] = (_Float16)be2[cc];
        }
    }

    // ---- init msgA: zeros, then constant 1.0 in col 47 (bias lane) ----
    for (int i = threadIdx.x; i < 64 * LDK; i += 256)
        (&msgA[0][0])[i] = (_Float16)0.f;
    __syncthreads();
    if (threadIdx.x < 64)
        msgA[threadIdx.x][swz(threadIdx.x, 47)] = (_Float16)1.0f;
    __syncthreads();

    // gather lane roles (r6 verbatim)
    const int xr = lane >> 2;
    const int xc = (lane & 3) * 8;
    const int eg = lane / 11, ec = lane - eg * 11;
    const bool ea_act  = lane < 44;
    const bool geo_act = lane < 48;

    for (int tile = blockIdx.x; tile < ntiles; tile += gridDim.x) {
        const int base = tile * 64 + row0;   // this wave's 16 CSR positions

        // ---- Phase 1: gather + commit (r6 verbatim; wave-private rows) ----
        {
            int p = base + xr;
            bool vx = p < E;
            int s = vx ? se[p].x : 0;
            const float4* xp = (const float4*)(x + (size_t)s * 32 + xc);
            float4 xa = xp[0];
            float4 xb = xp[1];

            float eav0 = 0.f, eav1 = 0.f, eav2 = 0.f, eav3 = 0.f;
            if (ea_act) {
                int p0 = base + 0 * 4 + eg, p1 = base + 1 * 4 + eg;
                int p2 = base + 2 * 4 + eg, p3 = base + 3 * 4 + eg;
                int e0 = (p0 < E) ? se[p0].y : 0;
                int e1 = (p1 < E) ? se[p1].y : 0;
                int e2 = (p2 < E) ? se[p2].y : 0;
                int e3 = (p3 < E) ? se[p3].y : 0;
                eav0 = (p0 < E) ? ea[(size_t)e0 * 11 + ec] : 0.f;
                eav1 = (p1 < E) ? ea[(size_t)e1 * 11 + ec] : 0.f;
                eav2 = (p2 < E) ? ea[(size_t)e2 * 11 + ec] : 0.f;
                eav3 = (p3 < E) ? ea[(size_t)e3 * 11 + ec] : 0.f;
            }

            float gpix = 0.f, gpiy = 0.f, gpiz = 0.f;
            float gpjx = 0.f, gpjy = 0.f, gpjz = 0.f;
            float gnix = 0.f, gniy = 0.f, gniz = 0.f;
            float gnjx = 0.f, gnjy = 0.f, gnjz = 0.f;
            int pd = -1;
            if (geo_act) {
                int pg = base + c16;
                bool v = pg < E;
                int s2 = v ? se[pg].x : 0;
                int d2 = v ? dst_g[pg] : 0;
                pd = v ? d2 : -1;
                gpix = pos[d2 * 3 + 0]; gpiy = pos[d2 * 3 + 1]; gpiz = pos[d2 * 3 + 2];
                gpjx = pos[s2 * 3 + 0]; gpjy = pos[s2 * 3 + 1]; gpjz = pos[s2 * 3 + 2];
                gnix = nrm[d2 * 3 + 0]; gniy = nrm[d2 * 3 + 1]; gniz = nrm[d2 * 3 + 2];
                gnjx = nrm[s2 * 3 + 0]; gnjy = nrm[s2 * 3 + 1]; gnjz = nrm[s2 * 3 + 2];
            }

            {
                int r = row0 + xr;
                f16x8 hv;
                hv[0] = (_Float16)(vx ? xa.x : 0.f); hv[1] = (_Float16)(vx ? xa.y : 0.f);
                hv[2] = (_Float16)(vx ? xa.z : 0.f); hv[3] = (_Float16)(vx ? xa.w : 0.f);
                hv[4] = (_Float16)(vx ? xb.x : 0.f); hv[5] = (_Float16)(vx ? xb.y : 0.f);
                hv[6] = (_Float16)(vx ? xb.z : 0.f); hv[7] = (_Float16)(vx ? xb.w : 0.f);
                *(f16x8*)&msgA[r][swz(r, xc)] = hv;
            }
            if (ea_act) {
                int r0 = row0 + 0 * 4 + eg; msgA[r0][swz(r0, 36 + ec)] = (_Float16)eav0;
                int r1 = row0 + 1 * 4 + eg; msgA[r1][swz(r1, 36 + ec)] = (_Float16)eav1;
                int r2 = row0 + 2 * 4 + eg; msgA[r2][swz(r2, 36 + ec)] = (_Float16)eav2;
                int r3 = row0 + 3 * 4 + eg; msgA[r3][swz(r3, 36 + ec)] = (_Float16)eav3;
            }
            if (geo_act) {
                int r = row0 + c16;
                float px = gpjx - gpix, py = gpjy - gpiy, pz = gpjz - gpiz;
                float v1x, v1y, v1z, v2x, v2y, v2z;
                if (g == 0)      { v1x = gnix; v1y = gniy; v1z = gniz; v2x = px;   v2y = py;   v2z = pz; }
                else if (g == 1) { v1x = gnjx; v1y = gnjy; v1z = gnjz; v2x = px;   v2y = py;   v2z = pz; }
                else             { v1x = gnix; v1y = gniy; v1z = gniz; v2x = gnjx; v2y = gnjy; v2z = gnjz; }
                float cx = v1y * v2z - v1z * v2y;
                float cy = v1z * v2x - v1x * v2z;
                float cz = v1x * v2y - v1y * v2x;
                float ang = atan2f(sqrtf(cx * cx + cy * cy + cz * cz),
                                   v1x * v2x + v1y * v2y + v1z * v2z);
                msgA[r][swz(r, 33 + g)] = (_Float16)ang;
                if (g == 0) {
                    msgA[r][swz(r, 32)] = (_Float16)sqrtf(px * px + py * py + pz * pz);
                    dstL[r] = pd;
                }
            }
        }
        // no barrier: all LDS rows above are wave-private

        const int ar = row0 + c16;   // this lane's edge row

        // ---- Phase 2: GEMM1 swapped (D = W1^T msg^T) + edge-local LN1 ----
        f32x4 acc1[3];
#pragma unroll
        for (int j = 0; j < 3; ++j) acc1[j] = (f32x4){0.f, 0.f, 0.f, 0.f};
#pragma unroll
        for (int ks = 0; ks < 2; ++ks) {
            f16x8 bfrag = *(const f16x8*)&msgA[ar][swz(ar, ks * 32 + g * 8)];
#pragma unroll
            for (int j = 0; j < 3; ++j)
                acc1[j] = __builtin_amdgcn_mfma_f32_16x16x32_f16(w1a[j][ks], bfrag, acc1[j], 0, 0, 0);
        }
        // lane (c16,g) holds D[ch = j*16+4g+q][edge = c16]; ch47 == 0 (A row zeroed)
        {
            float t1v[3][4];
            float s = 0.f, s2 = 0.f;
#pragma unroll
            for (int j = 0; j < 3; ++j)
#pragma unroll
                for (int q = 0; q < 4; ++q) {
                    float t = fmaxf(acc1[j][q], 0.f);
                    t1v[j][q] = t;
                    s += t; s2 += t * t;
                }
            s  += __shfl_xor(s, 16, 64);  s  += __shfl_xor(s, 32, 64);
            s2 += __shfl_xor(s2, 16, 64); s2 += __shfl_xor(s2, 32, 64);
            float mu  = s * (1.f / 47.f);
            float var = s2 * (1.f / 47.f) - mu * mu;
            float rs  = rsqrtf(var + 1e-5f);
#pragma unroll
            for (int j = 0; j < 3; ++j) {
                f16x4 hv;
#pragma unroll
                for (int q = 0; q < 4; ++q)
                    hv[q] = (_Float16)((t1v[j][q] - mu) * rs * (float)g1p[j][q]
                                       + (float)be1p[j][q]);
                if (j == 2 && g == 3) hv[3] = (_Float16)1.0f;   // col 47 = bias lane
                *(f16x4*)&msgA[ar][swz(ar, j * 16 + 4 * g)] = hv;   // ds_write_b64
            }
        }

        // ---- Phase 3: GEMM2 swapped + edge-local LN2 -> h2w[edge][ch] ----
        f32x4 acc2[8];
#pragma unroll
        for (int j = 0; j < 8; ++j) acc2[j] = (f32x4){0.f, 0.f, 0.f, 0.f};
#pragma unroll
        for (int ks = 0; ks < 2; ++ks) {
            f16x8 bfrag = *(const f16x8*)&msgA[ar][swz(ar, ks * 32 + g * 8)];
#pragma unroll
            for (int j = 0; j < 8; ++j)
                acc2[j] = __builtin_amdgcn_mfma_f32_16x16x32_f16(w2a[j][ks], bfrag, acc2[j], 0, 0, 0);
        }
        {
            float t2v[8][4];
            float s = 0.f, s2 = 0.f;
#pragma unroll
            for (int j = 0; j < 8; ++j)
#pragma unroll
                for (int q = 0; q < 4; ++q) {
                    float t = fmaxf(acc2[j][q], 0.f);
                    t2v[j][q] = t;
                    s += t; s2 += t * t;
                }
            s  += __shfl_xor(s, 16, 64);  s  += __shfl_xor(s, 32, 64);
            s2 += __shfl_xor(s2, 16, 64); s2 += __shfl_xor(s2, 32, 64);
            float mu  = s * (1.f / 128.f);
            float var = s2 * (1.f / 128.f) - mu * mu;
            float rs  = rsqrtf(var + 1e-5f);
#pragma unroll
            for (int j = 0; j < 8; ++j) {
                f16x4 hv;
#pragma unroll
                for (int q = 0; q < 4; ++q)
                    hv[q] = (_Float16)((t2v[j][q] - mu) * rs * (float)g2p[j][q]
                                       + (float)be2p[j][q]);
                *(f16x4*)&h2w[ar][j * 16 + 4 * g] = hv;   // ds_write_b64
            }
        }

        // ---- Phase 4: segmented max walk (r6 verbatim) ----
        {
            float m0 = -INFINITY, m1 = -INFINITY;
            int segStart = 0;
            int dcur = dstL[row0];
#pragma unroll
            for (int r = 0; r < 16; ++r) {
                f16x2 pk = *(const f16x2*)&h2w[row0 + r][lane * 2];
                m0 = fmaxf(m0, (float)pk[0]);
                m1 = fmaxf(m1, (float)pk[1]);
                int dnext = (r < 15) ? dstL[row0 + r + 1] : -2;
                if (dnext != dcur) {
                    if (dcur >= 0) {
                        unsigned e0 = fenc(m0), e1 = fenc(m1);
                        unsigned* orow = out + (size_t)dcur * 128 + lane * 2;
                        if (segStart > 0 && r < 15) {
                            unsigned long long pk2 =
                                ((unsigned long long)e1 << 32) | (unsigned long long)e0;
                            *(unsigned long long*)orow = pk2;
                        } else {
                            atomicMax(orow,     e0);
                            atomicMax(orow + 1, e1);
                        }
                    }
                    m0 = -INFINITY; m1 = -INFINITY;
                    segStart = r + 1; dcur = dnext;
                }
            }
        }
    }
}

// ---------------- fallback: direct atomics, no CSR (round-2 form) ----------------
#define LDKF 72
__global__ __launch_bounds__(256) void edge_kernel_atomic(
    const float* __restrict__ x,   const float* __restrict__ pos,
    const float* __restrict__ nrm, const float* __restrict__ ea,
    const float* __restrict__ W1,  const float* __restrict__ b1,
    const float* __restrict__ g1,  const float* __restrict__ be1,
    const float* __restrict__ W2,  const float* __restrict__ b2,
    const float* __restrict__ g2,  const float* __restrict__ be2,
    const int* __restrict__ srcI,  const int* __restrict__ dstI,
    unsigned* __restrict__ out, int E, int ntiles)
{
    __shared__ _Float16 W1t[48][LDKF];
    __shared__ _Float16 W2t[128][LDKF];
    __shared__ _Float16 msgA[64][LDKF];
    __shared__ int dst_s[64];

    const int lane = threadIdx.x & 63;
    const int w    = threadIdx.x >> 6;
    const int c16  = lane & 15;
    const int g    = lane >> 4;

    for (int i = threadIdx.x; i < 48 * 64; i += 256) {
        int n = i >> 6, k = i & 63;
        W1t[n][k] = (n < 47 && k < 47) ? (_Float16)W1[k * 47 + n] : (_Float16)0.f;
    }
    for (int i = threadIdx.x; i < 128 * 64; i += 256) {
        int n = i >> 6, k = i & 63;
        W2t[n][k] = (k < 47) ? (_Float16)W2[k * 128 + n] : (_Float16)0.f;
    }
    for (int i = threadIdx.x; i < 64 * LDKF; i += 256)
        (&msgA[0][0])[i] = (_Float16)0.f;

    float b1v[3], g1v[3], be1v[3];
#pragma unroll
    for (int n = 0; n < 3; ++n) {
        int cc = n * 16 + c16;
        bool vld = cc < 47;
        b1v[n]  = vld ? b1[cc]  : 0.f;
        g1v[n]  = vld ? g1[cc]  : 0.f;
        be1v[n] = vld ? be1[cc] : 0.f;
    }
    float b2v[8], g2v[8], be2v[8];
#pragma unroll
    for (int n = 0; n < 8; ++n) {
        int cc = n * 16 + c16;
        b2v[n] = b2[cc]; g2v[n] = g2[cc]; be2v[n] = be2[cc];
    }
    __syncthreads();

    for (int tile = blockIdx.x; tile < ntiles; tile += gridDim.x) {
        const int base = tile * 64 + w * 16;
        const int row0 = w * 16;
#pragma unroll
        for (int i = 0; i < 8; ++i) {
            int el = i * 2 + (lane >> 5);
            int e  = base + el;
            int c  = lane & 31;
            float v = 0.f;
            if (e < E) v = x[(size_t)srcI[e] * 32 + c];
            msgA[row0 + el][c] = (_Float16)v;
        }
        if (lane < 44) {
            int eg = lane / 11, c = lane - eg * 11;
#pragma unroll
            for (int i = 0; i < 4; ++i) {
                int el = i * 4 + eg;
                int e  = base + el;
                float v = 0.f;
                if (e < E) v = ea[(size_t)e * 11 + c];
                msgA[row0 + el][36 + c] = (_Float16)v;
            }
        }
        if (lane < 48) {
            int el = c16;
            int e  = base + el;
            int s = 0, d = 0;
            bool vld = e < E;
            if (vld) { s = srcI[e]; d = dstI[e]; }
            float pix = pos[d * 3 + 0], piy = pos[d * 3 + 1], piz = pos[d * 3 + 2];
            float pjx = pos[s * 3 + 0], pjy = pos[s * 3 + 1], pjz = pos[s * 3 + 2];
            float nix = nrm[d * 3 + 0], niy = nrm[d * 3 + 1], niz = nrm[d * 3 + 2];
            float njx = nrm[s * 3 + 0], njy = nrm[s * 3 + 1], njz = nrm[s * 3 + 2];
            float px = pjx - pix, py = pjy - piy, pz = pjz - piz;
            float v1x, v1y, v1z, v2x, v2y, v2z;
            if (g == 0)      { v1x = nix; v1y = niy; v1z = niz; v2x = px;  v2y = py;  v2z = pz;  }
            else if (g == 1) { v1x = njx; v1y = njy; v1z = njz; v2x = px;  v2y = py;  v2z = pz;  }
            else             { v1x = nix; v1y = niy; v1z = niz; v2x = njx; v2y = njy; v2z = njz; }
            float cx = v1y * v2z - v1z * v2y;
            float cy = v1z * v2x - v1x * v2z;
            float cz = v1x * v2y - v1y * v2x;
            float ang = atan2f(sqrtf(cx * cx + cy * cy + cz * cz),
                               v1x * v2x + v1y * v2y + v1z * v2z);
            msgA[row0 + el][33 + g] = (_Float16)ang;
            if (g == 0) {
                msgA[row0 + el][32] = (_Float16)sqrtf(px * px + py * py + pz * pz);
                dst_s[row0 + el] = vld ? d : -1;
            }
        }

        f32x4 acc1[3];
#pragma unroll
        for (int n = 0; n < 3; ++n) acc1[n] = (f32x4){0.f, 0.f, 0.f, 0.f};
#pragma unroll
        for (int ks = 0; ks < 2; ++ks) {
            f16x8 a = *(const f16x8*)&msgA[row0 + c16][ks * 32 + g * 8];
#pragma unroll
            for (int n = 0; n < 3; ++n) {
                f16x8 b = *(const f16x8*)&W1t[n * 16 + c16][ks * 32 + g * 8];
                acc1[n] = __builtin_amdgcn_mfma_f32_16x16x32_f16(a, b, acc1[n], 0, 0, 0);
            }
        }
#pragma unroll
        for (int q = 0; q < 4; ++q) {
            float t0 = fmaxf(acc1[0][q] + b1v[0], 0.f);
            float t1 = fmaxf(acc1[1][q] + b1v[1], 0.f);
            float t2 = fmaxf(acc1[2][q] + b1v[2], 0.f);
            float s = t0 + t1 + t2;
            float s2 = t0 * t0 + t1 * t1 + t2 * t2;
#pragma unroll
            for (int m = 1; m < 16; m <<= 1) {
                s  += __shfl_xor(s,  m, 64);
                s2 += __shfl_xor(s2, m, 64);
            }
            float mu  = s * (1.f / 47.f);
            float var = s2 * (1.f / 47.f) - mu * mu;
            float rs  = rsqrtf(var + 1e-5f);
            int r = row0 + 4 * g + q;
            msgA[r][c16]      = (_Float16)((t0 - mu) * rs * g1v[0] + be1v[0]);
            msgA[r][16 + c16] = (_Float16)((t1 - mu) * rs * g1v[1] + be1v[1]);
            msgA[r][32 + c16] = (_Float16)((t2 - mu) * rs * g1v[2] + be1v[2]);
        }

        f32x4 acc2[8];
#pragma unroll
        for (int n = 0; n < 8; ++n) acc2[n] = (f32x4){0.f, 0.f, 0.f, 0.f};
#pragma unroll
        for (int ks = 0; ks < 2; ++ks) {
            f16x8 a = *(const f16x8*)&msgA[row0 + c16][ks * 32 + g * 8];
#pragma unroll
            for (int n = 0; n < 8; ++n) {
                f16x8 b = *(const f16x8*)&W2t[n * 16 + c16][ks * 32 + g * 8];
                acc2[n] = __builtin_amdgcn_mfma_f32_16x16x32_f16(a, b, acc2[n], 0, 0, 0);
            }
        }
        int4 dd = *(const int4*)&dst_s[row0 + 4 * g];
#pragma unroll
        for (int q = 0; q < 4; ++q) {
            float t[8];
            float s = 0.f, s2 = 0.f;
#pragma unroll
            for (int n = 0; n < 8; ++n) {
                t[n] = fmaxf(acc2[n][q] + b2v[n], 0.f);
                s += t[n]; s2 += t[n] * t[n];
            }
#pragma unroll
            for (int m = 1; m < 16; m <<= 1) {
                s  += __shfl_xor(s,  m, 64);
                s2 += __shfl_xor(s2, m, 64);
            }
            float mu  = s * (1.f / 128.f);
            float var = s2 * (1.f / 128.f) - mu * mu;
            float rs  = rsqrtf(var + 1e-5f);
            int d = (&dd.x)[q];
            if (d >= 0) {
                unsigned* orow = out + (size_t)d * 128u;
#pragma unroll
                for (int n = 0; n < 8; ++n) {
                    float o = (t[n] - mu) * rs * g2v[n] + be2v[n];
                    atomicMax(orow + n * 16 + c16, fenc(o));
                }
            }
        }
    }
}

extern "C" void kernel_launch(void* const* d_in, const int* in_sizes, int n_in,
                              void* d_out, int out_size, void* d_ws, size_t ws_size,
                              hipStream_t stream) {
    const float* x   = (const float*)d_in[0];
    const float* pos = (const float*)d_in[1];
    const float* nrm = (const float*)d_in[2];
    const float* ea  = (const float*)d_in[3];
    const float* W1  = (const float*)d_in[4];
    const float* b1  = (const float*)d_in[5];
    const float* g1  = (const float*)d_in[6];
    const float* be1 = (const float*)d_in[7];
    const float* W2  = (const float*)d_in[8];
    const float* b2  = (const float*)d_in[9];
    const float* g2  = (const float*)d_in[10];
    const float* be2 = (const float*)d_in[11];
    const int*   idx = (const int*)d_in[12];

    const int N = in_sizes[0] / 32;
    const int E = in_sizes[3] / 11;
    const int* srcI = idx;
    const int* dstI = idx + E;

    unsigned* outU = (unsigned*)d_out;
    const int n = N * 128;

    init_out_kernel<<<(n / 4 + 255) / 256, 256, 0, stream>>>(outU, n / 4);

    const int nb = (N + 1023) / 1024;
    // ws layout: se[E] int2 | counts[N] | nextp[N] | dst_g[E] | bsums[nb]
    const size_t needed = (size_t)E * 8 + (size_t)(2LL * N + E + nb) * 4;
    const int ntiles = (E + 63) / 64;

    if (ws_size >= needed) {
        int2* se     = (int2*)d_ws;
        int*  counts = (int*)(se + E);
        int*  nextp  = counts + N;
        int*  dst_g  = nextp + N;
        int*  bsums  = dst_g + E;

        zero_kernel<<<(N + 255) / 256, 256, 0, stream>>>(counts, N);
        hist_kernel<<<(E + 255) / 256, 256, 0, stream>>>(dstI, counts, E);
        scan_blk<<<nb, 1024, 0, stream>>>(counts, nextp, bsums, N);
        scan_blk<<<1, 1024, 0, stream>>>(bsums, bsums, (int*)nullptr, nb);
        scan_add<<<nb, 1024, 0, stream>>>(nextp, bsums, N);
        scatter_kernel<<<(E + 255) / 256, 256, 0, stream>>>(srcI, dstI, nextp,
                                                            se, dst_g, E);

        int grid = ntiles < 1024 ? ntiles : 1024;
        edge_kernel_csr<<<grid, 256, 0, stream>>>(x, pos, nrm, ea,
                                                  W1, b1, g1, be1,
                                                  W2, b2, g2, be2,
                                                  se, dst_g,
                                                  outU, E, ntiles);
    } else {
        int grid = ntiles < 4096 ? ntiles : 4096;
        edge_kernel_atomic<<<grid, 256, 0, stream>>>(x, pos, nrm, ea,
                                                     W1, b1, g1, be1,
                                                     W2, b2, g2, be2,
                                                     srcI, dstI, outU, E, ntiles);
    }

    finalize_out_kernel<<<(n + 255) / 256, 256, 0, stream>>>((float*)d_out, n);
}

// Round 10
// 852.842 us; speedup vs baseline: 1.7835x; 1.7835x over previous
//
#include <hip/hip_runtime.h>
#include <cstdint>
#include <cstddef>

// ---------------------------------------------------------------------------
// DockPointNet fused edge-MLP + segment-max, f16 MFMA + CSR counting sort.
// Round 10 = round 9 with the cvt_pkrtz type fixed (__fp16 vec -> bit_cast).
//   (1) LN2 apply in packed f16 (cvt_pkrtz + v_pk_fma_f16) -- r6 is
//       VALU-issue-bound (53% busy, ~900 VALU/window); LN2 apply was the
//       largest block (~160/window).
//   (2) walk max in f16 (drop 2 cvts/row; decode only at segment emit).
//   (3) scan_add fused into scatter; finalize vectorized uint4.
// r8 lesson: unified regfile (VGPR+AGPR) <= 128 keeps 4 waves/SIMD; weights
// stay in LDS. All layouts identical to r6.
// ---------------------------------------------------------------------------

typedef _Float16 f16x8 __attribute__((ext_vector_type(8)));
typedef _Float16 f16x2 __attribute__((ext_vector_type(2)));
typedef float    f32x4 __attribute__((ext_vector_type(4)));

#define ENC_NEGINF 0x007FFFFFu   // fenc(-inf)
#define LDK 64                   // msg/W row stride (f16), swizzled
#define LDH 132                  // h2 row stride (f16)

__device__ __forceinline__ int swz(int row, int col) {
    return (col & 7) | ((((col >> 3) ^ row) & 7) << 3);
}

__device__ __forceinline__ unsigned fenc(float f) {
    unsigned u = __float_as_uint(f);
    return (u & 0x80000000u) ? ~u : (u | 0x80000000u);
}

__device__ __forceinline__ float fdec(unsigned k) {
    if (k == ENC_NEGINF) return 0.0f;
    unsigned u = (k & 0x80000000u) ? (k ^ 0x80000000u) : ~k;
    return __uint_as_float(u);
}

__device__ __forceinline__ f16x2 pkrtz(float a, float b) {
    auto p = __builtin_amdgcn_cvt_pkrtz(a, b);   // __fp16 ext_vector(2)
    return __builtin_bit_cast(f16x2, p);
}

__global__ void init_out_kernel(unsigned* __restrict__ out, int n4) {
    int i = blockIdx.x * blockDim.x + threadIdx.x;
    if (i < n4)
        ((uint4*)out)[i] = make_uint4(ENC_NEGINF, ENC_NEGINF, ENC_NEGINF, ENC_NEGINF);
}

__global__ void finalize_out_kernel(float* __restrict__ out, int n4) {
    int i = blockIdx.x * blockDim.x + threadIdx.x;
    if (i < n4) {
        uint4 k = ((const uint4*)out)[i];
        float4 r;
        r.x = fdec(k.x); r.y = fdec(k.y); r.z = fdec(k.z); r.w = fdec(k.w);
        ((float4*)out)[i] = r;
    }
}

// ---------------- CSR build ----------------
__global__ void zero_kernel(int* __restrict__ p, int n) {
    int i = blockIdx.x * blockDim.x + threadIdx.x;
    if (i < n) p[i] = 0;
}

__global__ void hist_kernel(const int* __restrict__ dstI, int* __restrict__ counts, int E) {
    int i = blockIdx.x * blockDim.x + threadIdx.x;
    if (i < E) atomicAdd(&counts[dstI[i]], 1);
}

// exclusive scan of one 1024-chunk per block; optional per-block totals.
__global__ __launch_bounds__(1024) void scan_blk(const int* __restrict__ in,
                                                 int* __restrict__ outp,
                                                 int* __restrict__ bsums, int N) {
    __shared__ int wsum[16];
    const int tid = threadIdx.x, lane = tid & 63, wid = tid >> 6;
    int i = blockIdx.x * 1024 + tid;
    int v = (i < N) ? in[i] : 0;
    int incl = v;
#pragma unroll
    for (int m = 1; m < 64; m <<= 1) {
        int t = __shfl_up(incl, m, 64);
        if (lane >= m) incl += t;
    }
    if (lane == 63) wsum[wid] = incl;
    __syncthreads();
    int woff = 0;
#pragma unroll
    for (int k = 0; k < 16; ++k) woff += (k < wid) ? wsum[k] : 0;
    if (i < N) outp[i] = woff + incl - v;
    if (tid == 1023 && bsums != nullptr) bsums[blockIdx.x] = woff + incl;
}

// scatter with fused top-level offset (bsums already scanned): one pass less.
__global__ void scatter_kernel(const int* __restrict__ srcI, const int* __restrict__ dstI,
                               int* __restrict__ nextp, const int* __restrict__ bsums,
                               int2* __restrict__ se, int* __restrict__ dst_g, int E) {
    int i = blockIdx.x * blockDim.x + threadIdx.x;
    if (i < E) {
        int d = dstI[i];
        int p = bsums[d >> 10] + atomicAdd(&nextp[d], 1);
        se[p] = make_int2(srcI[i], i);
        dst_g[p] = d;
    }
}

// ---------------- CSR edge kernel: 8 waves/block (r6 structure) ----------
__global__ __launch_bounds__(512, 4) void edge_kernel_csr(
    const float* __restrict__ x,   const float* __restrict__ pos,
    const float* __restrict__ nrm, const float* __restrict__ ea,
    const float* __restrict__ W1,  const float* __restrict__ b1,
    const float* __restrict__ g1,  const float* __restrict__ be1,
    const float* __restrict__ W2,  const float* __restrict__ b2,
    const float* __restrict__ g2,  const float* __restrict__ be2,
    const int2* __restrict__ se,   const int* __restrict__ dst_g,
    unsigned* __restrict__ out, int E, int ntiles, int tilesPerBlock)
{
    __shared__ _Float16 W1t[48][LDK];     // 6.0 KB  (swizzled [n][k])
    __shared__ _Float16 W2t[128][LDK];    // 16.0 KB
    __shared__ _Float16 msgA[128][LDK];   // 16.0 KB (msg; h1 aliased after GEMM1)
    __shared__ _Float16 h2w[128][LDH];    // 33.0 KB (linear; walk is 2-way = free)
    __shared__ int dstL[128];

    const int lane = threadIdx.x & 63;
    const int w    = threadIdx.x >> 6;   // 0..7
    const int c16  = lane & 15;
    const int g    = lane >> 4;
    const int row0 = w * 16;

    // ---- stage weights (f16, transposed, zero-padded, swizzled) ----
    for (int i = threadIdx.x; i < 48 * 64; i += 512) {
        int n = i >> 6, k = i & 63;
        W1t[n][swz(n, k)] = (n < 47 && k < 47) ? (_Float16)W1[k * 47 + n] : (_Float16)0.f;
    }
    for (int i = threadIdx.x; i < 128 * 64; i += 512) {
        int n = i >> 6, k = i & 63;
        W2t[n][swz(n, k)] = (k < 47) ? (_Float16)W2[k * 128 + n] : (_Float16)0.f;
    }
    for (int i = threadIdx.x; i < 128 * LDK; i += 512)
        (&msgA[0][0])[i] = (_Float16)0.f;

    // ---- per-lane LN params ----
    float b1v[3], g1v[3], be1v[3];
#pragma unroll
    for (int n = 0; n < 3; ++n) {
        int cc = n * 16 + c16;
        bool vld = cc < 47;
        b1v[n]  = vld ? b1[cc]  : 0.f;
        g1v[n]  = vld ? g1[cc]  : 0.f;
        be1v[n] = vld ? be1[cc] : 0.f;
    }
    float b2v[8];
    f16x2 g2pk[4], be2pk[4];   // packed pairs: channels (2h)*16+c16, (2h+1)*16+c16
#pragma unroll
    for (int n = 0; n < 8; ++n) b2v[n] = b2[n * 16 + c16];
#pragma unroll
    for (int h = 0; h < 4; ++h) {
        g2pk[h][0]  = (_Float16)g2[(2 * h) * 16 + c16];
        g2pk[h][1]  = (_Float16)g2[(2 * h + 1) * 16 + c16];
        be2pk[h][0] = (_Float16)be2[(2 * h) * 16 + c16];
        be2pk[h][1] = (_Float16)be2[(2 * h + 1) * 16 + c16];
    }
    __syncthreads();

    // gather lane roles
    const int xr = lane >> 2;            // x: row within wave's 16 edges
    const int xc = (lane & 3) * 8;       //    8 channels per lane
    const int eg = lane / 11, ec = lane - eg * 11;   // ea: lanes<44
    const bool ea_act  = lane < 44;
    const bool geo_act = lane < 48;

    const int tbeg = blockIdx.x * tilesPerBlock;
    int tend = tbeg + tilesPerBlock;
    if (tend > ntiles) tend = ntiles;

    for (int tile = tbeg; tile < tend; ++tile) {
        const int base = tile * 128 + row0;   // this wave's 16 CSR positions

        // ---- Phase 1: gather (all loads issued as one batch) + commit ----
        {
            int p = base + xr;
            bool vx = p < E;
            int s = vx ? se[p].x : 0;
            const float4* xp = (const float4*)(x + (size_t)s * 32 + xc);
            float4 xa = xp[0];
            float4 xb = xp[1];

            float eav0 = 0.f, eav1 = 0.f, eav2 = 0.f, eav3 = 0.f;
            if (ea_act) {
                int p0 = base + 0 * 4 + eg, p1 = base + 1 * 4 + eg;
                int p2 = base + 2 * 4 + eg, p3 = base + 3 * 4 + eg;
                int e0 = (p0 < E) ? se[p0].y : 0;
                int e1 = (p1 < E) ? se[p1].y : 0;
                int e2 = (p2 < E) ? se[p2].y : 0;
                int e3 = (p3 < E) ? se[p3].y : 0;
                eav0 = (p0 < E) ? ea[(size_t)e0 * 11 + ec] : 0.f;
                eav1 = (p1 < E) ? ea[(size_t)e1 * 11 + ec] : 0.f;
                eav2 = (p2 < E) ? ea[(size_t)e2 * 11 + ec] : 0.f;
                eav3 = (p3 < E) ? ea[(size_t)e3 * 11 + ec] : 0.f;
            }

            float gpix = 0.f, gpiy = 0.f, gpiz = 0.f;
            float gpjx = 0.f, gpjy = 0.f, gpjz = 0.f;
            float gnix = 0.f, gniy = 0.f, gniz = 0.f;
            float gnjx = 0.f, gnjy = 0.f, gnjz = 0.f;
            int pd = -1;
            if (geo_act) {
                int pg = base + c16;
                bool v = pg < E;
                int s2 = v ? se[pg].x : 0;
                int d2 = v ? dst_g[pg] : 0;
                pd = v ? d2 : -1;
                gpix = pos[d2 * 3 + 0]; gpiy = pos[d2 * 3 + 1]; gpiz = pos[d2 * 3 + 2];
                gpjx = pos[s2 * 3 + 0]; gpjy = pos[s2 * 3 + 1]; gpjz = pos[s2 * 3 + 2];
                gnix = nrm[d2 * 3 + 0]; gniy = nrm[d2 * 3 + 1]; gniz = nrm[d2 * 3 + 2];
                gnjx = nrm[s2 * 3 + 0]; gnjy = nrm[s2 * 3 + 1]; gnjz = nrm[s2 * 3 + 2];
            }

            // commit x
            {
                int r = row0 + xr;
                f16x8 hv;
                hv[0] = (_Float16)(vx ? xa.x : 0.f); hv[1] = (_Float16)(vx ? xa.y : 0.f);
                hv[2] = (_Float16)(vx ? xa.z : 0.f); hv[3] = (_Float16)(vx ? xa.w : 0.f);
                hv[4] = (_Float16)(vx ? xb.x : 0.f); hv[5] = (_Float16)(vx ? xb.y : 0.f);
                hv[6] = (_Float16)(vx ? xb.z : 0.f); hv[7] = (_Float16)(vx ? xb.w : 0.f);
                *(f16x8*)&msgA[r][swz(r, xc)] = hv;
            }
            // commit ea
            if (ea_act) {
                int r0 = row0 + 0 * 4 + eg; msgA[r0][swz(r0, 36 + ec)] = (_Float16)eav0;
                int r1 = row0 + 1 * 4 + eg; msgA[r1][swz(r1, 36 + ec)] = (_Float16)eav1;
                int r2 = row0 + 2 * 4 + eg; msgA[r2][swz(r2, 36 + ec)] = (_Float16)eav2;
                int r3 = row0 + 3 * 4 + eg; msgA[r3][swz(r3, 36 + ec)] = (_Float16)eav3;
            }
            // commit geometry (angle g per lane group)
            if (geo_act) {
                int r = row0 + c16;
                float px = gpjx - gpix, py = gpjy - gpiy, pz = gpjz - gpiz;
                float v1x, v1y, v1z, v2x, v2y, v2z;
                if (g == 0)      { v1x = gnix; v1y = gniy; v1z = gniz; v2x = px;   v2y = py;   v2z = pz; }
                else if (g == 1) { v1x = gnjx; v1y = gnjy; v1z = gnjz; v2x = px;   v2y = py;   v2z = pz; }
                else             { v1x = gnix; v1y = gniy; v1z = gniz; v2x = gnjx; v2y = gnjy; v2z = gnjz; }
                float cx = v1y * v2z - v1z * v2y;
                float cy = v1z * v2x - v1x * v2z;
                float cz = v1x * v2y - v1y * v2x;
                float ang = atan2f(sqrtf(cx * cx + cy * cy + cz * cz),
                                   v1x * v2x + v1y * v2y + v1z * v2z);
                msgA[r][swz(r, 33 + g)] = (_Float16)ang;
                if (g == 0) {
                    msgA[r][swz(r, 32)] = (_Float16)sqrtf(px * px + py * py + pz * pz);
                    dstL[r] = pd;
                }
            }
        }
        // no barrier: all LDS rows above are wave-private

        // ---- Phase 2: GEMM1 (16x48) + LN1 -> h1 back into msgA ----
        f32x4 acc1[3];
#pragma unroll
        for (int n = 0; n < 3; ++n) acc1[n] = (f32x4){0.f, 0.f, 0.f, 0.f};
#pragma unroll
        for (int ks = 0; ks < 2; ++ks) {
            int ar = row0 + c16;
            f16x8 a = *(const f16x8*)&msgA[ar][swz(ar, ks * 32 + g * 8)];
#pragma unroll
            for (int n = 0; n < 3; ++n) {
                int br = n * 16 + c16;
                f16x8 b = *(const f16x8*)&W1t[br][swz(br, ks * 32 + g * 8)];
                acc1[n] = __builtin_amdgcn_mfma_f32_16x16x32_f16(a, b, acc1[n], 0, 0, 0);
            }
        }
#pragma unroll
        for (int q = 0; q < 4; ++q) {
            float t0 = fmaxf(acc1[0][q] + b1v[0], 0.f);
            float t1 = fmaxf(acc1[1][q] + b1v[1], 0.f);
            float t2 = fmaxf(acc1[2][q] + b1v[2], 0.f);   // col 47 -> 0
            float s = t0 + t1 + t2;
            float s2 = t0 * t0 + t1 * t1 + t2 * t2;
#pragma unroll
            for (int m = 1; m < 16; m <<= 1) {
                s  += __shfl_xor(s,  m, 64);
                s2 += __shfl_xor(s2, m, 64);
            }
            float mu  = s * (1.f / 47.f);
            float var = s2 * (1.f / 47.f) - mu * mu;
            float rs  = rsqrtf(var + 1e-5f);
            int r = row0 + 4 * g + q;
            msgA[r][swz(r, c16)]      = (_Float16)((t0 - mu) * rs * g1v[0] + be1v[0]);
            msgA[r][swz(r, 16 + c16)] = (_Float16)((t1 - mu) * rs * g1v[1] + be1v[1]);
            msgA[r][swz(r, 32 + c16)] = (_Float16)((t2 - mu) * rs * g1v[2] + be1v[2]);
        }

        // ---- Phase 3: GEMM2 (16x128) + LN2 (packed-f16 apply) -> h2w ----
        f32x4 acc2[8];
#pragma unroll
        for (int n = 0; n < 8; ++n) acc2[n] = (f32x4){0.f, 0.f, 0.f, 0.f};
#pragma unroll
        for (int ks = 0; ks < 2; ++ks) {
            int ar = row0 + c16;
            f16x8 a = *(const f16x8*)&msgA[ar][swz(ar, ks * 32 + g * 8)];
#pragma unroll
            for (int n = 0; n < 8; ++n) {
                int br = n * 16 + c16;
                f16x8 b = *(const f16x8*)&W2t[br][swz(br, ks * 32 + g * 8)];
                acc2[n] = __builtin_amdgcn_mfma_f32_16x16x32_f16(a, b, acc2[n], 0, 0, 0);
            }
        }
#pragma unroll
        for (int q = 0; q < 4; ++q) {
            float t[8];
            float s = 0.f, s2 = 0.f;
#pragma unroll
            for (int n = 0; n < 8; ++n) {
                t[n] = fmaxf(acc2[n][q] + b2v[n], 0.f);
                s += t[n]; s2 += t[n] * t[n];
            }
#pragma unroll
            for (int m = 1; m < 16; m <<= 1) {
                s  += __shfl_xor(s,  m, 64);
                s2 += __shfl_xor(s2, m, 64);
            }
            float mu  = s * (1.f / 128.f);
            float var = s2 * (1.f / 128.f) - mu * mu;
            float rs  = rsqrtf(var + 1e-5f);
            int r = row0 + 4 * g + q;
            // packed apply: h = (t*rs - mu*rs)*gamma + beta, two v_pk_fma_f16
            f16x2 apk = pkrtz(rs, rs);
            f16x2 cpk = pkrtz(-mu * rs, -mu * rs);
#pragma unroll
            for (int h = 0; h < 4; ++h) {
                f16x2 tpk = pkrtz(t[2 * h], t[2 * h + 1]);
                f16x2 z   = tpk * apk + cpk;
                f16x2 hvp = z * g2pk[h] + be2pk[h];
                h2w[r][(2 * h) * 16 + c16]     = hvp[0];
                h2w[r][(2 * h + 1) * 16 + c16] = hvp[1];
            }
        }

        // ---- Phase 4: segmented max walk (f16 max; decode at emit only) ----
        {
            f16x2 mneg; mneg[0] = mneg[1] = (_Float16)(-65504.f);
            f16x2 mx = mneg;
            int segStart = 0;
            int dcur = dstL[row0];
#pragma unroll
            for (int r = 0; r < 16; ++r) {
                f16x2 pk = *(const f16x2*)&h2w[row0 + r][lane * 2];
                mx[0] = (pk[0] > mx[0]) ? pk[0] : mx[0];
                mx[1] = (pk[1] > mx[1]) ? pk[1] : mx[1];
                int dnext = (r < 15) ? dstL[row0 + r + 1] : -2;
                if (dnext != dcur) {
                    if (dcur >= 0) {
                        unsigned e0 = fenc((float)mx[0]);
                        unsigned e1 = fenc((float)mx[1]);
                        unsigned* orow = out + (size_t)dcur * 128 + lane * 2;
                        if (segStart > 0 && r < 15) {
                            unsigned long long pk2 =
                                ((unsigned long long)e1 << 32) | (unsigned long long)e0;
                            *(unsigned long long*)orow = pk2;
                        } else {
                            atomicMax(orow,     e0);
                            atomicMax(orow + 1, e1);
                        }
                    }
                    mx = mneg;
                    segStart = r + 1; dcur = dnext;
                }
            }
        }
    }
}

// ---------------- fallback: direct atomics, no CSR (round-2 form) ----------------
#define LDKF 72
__global__ __launch_bounds__(256) void edge_kernel_atomic(
    const float* __restrict__ x,   const float* __restrict__ pos,
    const float* __restrict__ nrm, const float* __restrict__ ea,
    const float* __restrict__ W1,  const float* __restrict__ b1,
    const float* __restrict__ g1,  const float* __restrict__ be1,
    const float* __restrict__ W2,  const float* __restrict__ b2,
    const float* __restrict__ g2,  const float* __restrict__ be2,
    const int* __restrict__ srcI,  const int* __restrict__ dstI,
    unsigned* __restrict__ out, int E, int ntiles)
{
    __shared__ _Float16 W1t[48][LDKF];
    __shared__ _Float16 W2t[128][LDKF];
    __shared__ _Float16 msgA[64][LDKF];
    __shared__ int dst_s[64];

    const int lane = threadIdx.x & 63;
    const int w    = threadIdx.x >> 6;
    const int c16  = lane & 15;
    const int g    = lane >> 4;

    for (int i = threadIdx.x; i < 48 * 64; i += 256) {
        int n = i >> 6, k = i & 63;
        W1t[n][k] = (n < 47 && k < 47) ? (_Float16)W1[k * 47 + n] : (_Float16)0.f;
    }
    for (int i = threadIdx.x; i < 128 * 64; i += 256) {
        int n = i >> 6, k = i & 63;
        W2t[n][k] = (k < 47) ? (_Float16)W2[k * 128 + n] : (_Float16)0.f;
    }
    for (int i = threadIdx.x; i < 64 * LDKF; i += 256)
        (&msgA[0][0])[i] = (_Float16)0.f;

    float b1v[3], g1v[3], be1v[3];
#pragma unroll
    for (int n = 0; n < 3; ++n) {
        int cc = n * 16 + c16;
        bool vld = cc < 47;
        b1v[n]  = vld ? b1[cc]  : 0.f;
        g1v[n]  = vld ? g1[cc]  : 0.f;
        be1v[n] = vld ? be1[cc] : 0.f;
    }
    float b2v[8], g2v[8], be2v[8];
#pragma unroll
    for (int n = 0; n < 8; ++n) {
        int cc = n * 16 + c16;
        b2v[n] = b2[cc]; g2v[n] = g2[cc]; be2v[n] = be2[cc];
    }
    __syncthreads();

    for (int tile = blockIdx.x; tile < ntiles; tile += gridDim.x) {
        const int base = tile * 64 + w * 16;
        const int row0 = w * 16;
#pragma unroll
        for (int i = 0; i < 8; ++i) {
            int el = i * 2 + (lane >> 5);
            int e  = base + el;
            int c  = lane & 31;
            float v = 0.f;
            if (e < E) v = x[(size_t)srcI[e] * 32 + c];
            msgA[row0 + el][c] = (_Float16)v;
        }
        if (lane < 44) {
            int eg = lane / 11, c = lane - eg * 11;
#pragma unroll
            for (int i = 0; i < 4; ++i) {
                int el = i * 4 + eg;
                int e  = base + el;
                float v = 0.f;
                if (e < E) v = ea[(size_t)e * 11 + c];
                msgA[row0 + el][36 + c] = (_Float16)v;
            }
        }
        if (lane < 48) {
            int el = c16;
            int e  = base + el;
            int s = 0, d = 0;
            bool vld = e < E;
            if (vld) { s = srcI[e]; d = dstI[e]; }
            float pix = pos[d * 3 + 0], piy = pos[d * 3 + 1], piz = pos[d * 3 + 2];
            float pjx = pos[s * 3 + 0], pjy = pos[s * 3 + 1], pjz = pos[s * 3 + 2];
            float nix = nrm[d * 3 + 0], niy = nrm[d * 3 + 1], niz = nrm[d * 3 + 2];
            float njx = nrm[s * 3 + 0], njy = nrm[s * 3 + 1], njz = nrm[s * 3 + 2];
            float px = pjx - pix, py = pjy - piy, pz = pjz - piz;
            float v1x, v1y, v1z, v2x, v2y, v2z;
            if (g == 0)      { v1x = nix; v1y = niy; v1z = niz; v2x = px;  v2y = py;  v2z = pz;  }
            else if (g == 1) { v1x = njx; v1y = njy; v1z = njz; v2x = px;  v2y = py;  v2z = pz;  }
            else             { v1x = nix; v1y = niy; v1z = niz; v2x = njx; v2y = njy; v2z = njz; }
            float cx = v1y * v2z - v1z * v2y;
            float cy = v1z * v2x - v1x * v2z;
            float cz = v1x * v2y - v1y * v2x;
            float ang = atan2f(sqrtf(cx * cx + cy * cy + cz * cz),
                               v1x * v2x + v1y * v2y + v1z * v2z);
            msgA[row0 + el][33 + g] = (_Float16)ang;
            if (g == 0) {
                msgA[row0 + el][32] = (_Float16)sqrtf(px * px + py * py + pz * pz);
                dst_s[row0 + el] = vld ? d : -1;
            }
        }

        f32x4 acc1[3];
#pragma unroll
        for (int n = 0; n < 3; ++n) acc1[n] = (f32x4){0.f, 0.f, 0.f, 0.f};
#pragma unroll
        for (int ks = 0; ks < 2; ++ks) {
            f16x8 a = *(const f16x8*)&msgA[row0 + c16][ks * 32 + g * 8];
#pragma unroll
            for (int n = 0; n < 3; ++n) {
                f16x8 b = *(const f16x8*)&W1t[n * 16 + c16][ks * 32 + g * 8];
                acc1[n] = __builtin_amdgcn_mfma_f32_16x16x32_f16(a, b, acc1[n], 0, 0, 0);
            }
        }
#pragma unroll
        for (int q = 0; q < 4; ++q) {
            float t0 = fmaxf(acc1[0][q] + b1v[0], 0.f);
            float t1 = fmaxf(acc1[1][q] + b1v[1], 0.f);
            float t2 = fmaxf(acc1[2][q] + b1v[2], 0.f);
            float s = t0 + t1 + t2;
            float s2 = t0 * t0 + t1 * t1 + t2 * t2;
#pragma unroll
            for (int m = 1; m < 16; m <<= 1) {
                s  += __shfl_xor(s,  m, 64);
                s2 += __shfl_xor(s2, m, 64);
            }
            float mu  = s * (1.f / 47.f);
            float var = s2 * (1.f / 47.f) - mu * mu;
            float rs  = rsqrtf(var + 1e-5f);
            int r = row0 + 4 * g + q;
            msgA[r][c16]      = (_Float16)((t0 - mu) * rs * g1v[0] + be1v[0]);
            msgA[r][16 + c16] = (_Float16)((t1 - mu) * rs * g1v[1] + be1v[1]);
            msgA[r][32 + c16] = (_Float16)((t2 - mu) * rs * g1v[2] + be1v[2]);
        }

        f32x4 acc2[8];
#pragma unroll
        for (int n = 0; n < 8; ++n) acc2[n] = (f32x4){0.f, 0.f, 0.f, 0.f};
#pragma unroll
        for (int ks = 0; ks < 2; ++ks) {
            f16x8 a = *(const f16x8*)&msgA[row0 + c16][ks * 32 + g * 8];
#pragma unroll
            for (int n = 0; n < 8; ++n) {
                f16x8 b = *(const f16x8*)&W2t[n * 16 + c16][ks * 32 + g * 8];
                acc2[n] = __builtin_amdgcn_mfma_f32_16x16x32_f16(a, b, acc2[n], 0, 0, 0);
            }
        }
        int4 dd = *(const int4*)&dst_s[row0 + 4 * g];
#pragma unroll
        for (int q = 0; q < 4; ++q) {
            float t[8];
            float s = 0.f, s2 = 0.f;
#pragma unroll
            for (int n = 0; n < 8; ++n) {
                t[n] = fmaxf(acc2[n][q] + b2v[n], 0.f);
                s += t[n]; s2 += t[n] * t[n];
            }
#pragma unroll
            for (int m = 1; m < 16; m <<= 1) {
                s  += __shfl_xor(s,  m, 64);
                s2 += __shfl_xor(s2, m, 64);
            }
            float mu  = s * (1.f / 128.f);
            float var = s2 * (1.f / 128.f) - mu * mu;
            float rs  = rsqrtf(var + 1e-5f);
            int d = (&dd.x)[q];
            if (d >= 0) {
                unsigned* orow = out + (size_t)d * 128u;
#pragma unroll
                for (int n = 0; n < 8; ++n) {
                    float o = (t[n] - mu) * rs * g2v[n] + be2v[n];
                    atomicMax(orow + n * 16 + c16, fenc(o));
                }
            }
        }
    }
}

extern "C" void kernel_launch(void* const* d_in, const int* in_sizes, int n_in,
                              void* d_out, int out_size, void* d_ws, size_t ws_size,
                              hipStream_t stream) {
    const float* x   = (const float*)d_in[0];
    const float* pos = (const float*)d_in[1];
    const float* nrm = (const float*)d_in[2];
    const float* ea  = (const float*)d_in[3];
    const float* W1  = (const float*)d_in[4];
    const float* b1  = (const float*)d_in[5];
    const float* g1  = (const float*)d_in[6];
    const float* be1 = (const float*)d_in[7];
    const float* W2  = (const float*)d_in[8];
    const float* b2  = (const float*)d_in[9];
    const float* g2  = (const float*)d_in[10];
    const float* be2 = (const float*)d_in[11];
    const int*   idx = (const int*)d_in[12];

    const int N = in_sizes[0] / 32;
    const int E = in_sizes[3] / 11;
    const int* srcI = idx;
    const int* dstI = idx + E;

    unsigned* outU = (unsigned*)d_out;
    const int n = N * 128;

    init_out_kernel<<<(n / 4 + 255) / 256, 256, 0, stream>>>(outU, n / 4);

    const int nb = (N + 1023) / 1024;
    // ws layout: se[E] int2 | counts[N] | nextp[N] | dst_g[E] | bsums[nb]
    const size_t needed = (size_t)E * 8 + (size_t)(2LL * N + E + nb) * 4;

    if (ws_size >= needed) {
        int2* se     = (int2*)d_ws;
        int*  counts = (int*)(se + E);
        int*  nextp  = counts + N;
        int*  dst_g  = nextp + N;
        int*  bsums  = dst_g + E;

        zero_kernel<<<(N + 255) / 256, 256, 0, stream>>>(counts, N);
        hist_kernel<<<(E + 255) / 256, 256, 0, stream>>>(dstI, counts, E);
        scan_blk<<<nb, 1024, 0, stream>>>(counts, nextp, bsums, N);
        scan_blk<<<1, 1024, 0, stream>>>(bsums, bsums, (int*)nullptr, nb);
        scatter_kernel<<<(E + 255) / 256, 256, 0, stream>>>(srcI, dstI, nextp, bsums,
                                                            se, dst_g, E);

        const int ntiles = (E + 127) / 128;
        int grid = ntiles < 512 ? ntiles : 512;    // 2 blocks/CU resident, persistent
        int tpb  = (ntiles + grid - 1) / grid;
        edge_kernel_csr<<<grid, 512, 0, stream>>>(x, pos, nrm, ea,
                                                  W1, b1, g1, be1,
                                                  W2, b2, g2, be2,
                                                  se, dst_g,
                                                  outU, E, ntiles, tpb);
    } else {
        const int ntiles = (E + 63) / 64;
        int grid = ntiles < 4096 ? ntiles : 4096;
        edge_kernel_atomic<<<grid, 256, 0, stream>>>(x, pos, nrm, ea,
                                                     W1, b1, g1, be1,
                                                     W2, b2, g2, be2,
                                                     srcI, dstI, outU, E, ntiles);
    }

    finalize_out_kernel<<<(n / 4 + 255) / 256, 256, 0, stream>>>((float*)d_out, n / 4);
}

// Round 11
// 842.294 us; speedup vs baseline: 1.8059x; 1.0125x over previous
//
#include <hip/hip_runtime.h>
#include <cstdint>
#include <cstddef>

// ---------------------------------------------------------------------------
// DockPointNet fused edge-MLP + segment-max, f16 MFMA + CSR counting sort.
// Round 11 = round 10 + cross-tile prefetch of the two longest latency poles:
//   level-1 CSR indices (se, dst_g: 25.6MB stream, L2-miss ~600cy) and
//   ea values (140MB footprint, HBM ~900cy). r10 profile: nothing saturated
//   (VALU 51, DS ~15, MFMA 6) at the 42% occupancy cap -> latency-bound.
// r5 lesson applied: NAMED SCALARS only (no arrays/lambdas -> no scratch);
// only 11 extra live regs (~119 unified, keeps 4 waves/SIMD).
// ---------------------------------------------------------------------------

typedef _Float16 f16x8 __attribute__((ext_vector_type(8)));
typedef _Float16 f16x2 __attribute__((ext_vector_type(2)));
typedef float    f32x4 __attribute__((ext_vector_type(4)));

#define ENC_NEGINF 0x007FFFFFu   // fenc(-inf)
#define LDK 64                   // msg/W row stride (f16), swizzled
#define LDH 132                  // h2 row stride (f16)

__device__ __forceinline__ int swz(int row, int col) {
    return (col & 7) | ((((col >> 3) ^ row) & 7) << 3);
}

__device__ __forceinline__ unsigned fenc(float f) {
    unsigned u = __float_as_uint(f);
    return (u & 0x80000000u) ? ~u : (u | 0x80000000u);
}

__device__ __forceinline__ float fdec(unsigned k) {
    if (k == ENC_NEGINF) return 0.0f;
    unsigned u = (k & 0x80000000u) ? (k ^ 0x80000000u) : ~k;
    return __uint_as_float(u);
}

__device__ __forceinline__ f16x2 pkrtz(float a, float b) {
    auto p = __builtin_amdgcn_cvt_pkrtz(a, b);   // __fp16 ext_vector(2)
    return __builtin_bit_cast(f16x2, p);
}

__global__ void init_out_kernel(unsigned* __restrict__ out, int n4) {
    int i = blockIdx.x * blockDim.x + threadIdx.x;
    if (i < n4)
        ((uint4*)out)[i] = make_uint4(ENC_NEGINF, ENC_NEGINF, ENC_NEGINF, ENC_NEGINF);
}

__global__ void finalize_out_kernel(float* __restrict__ out, int n4) {
    int i = blockIdx.x * blockDim.x + threadIdx.x;
    if (i < n4) {
        uint4 k = ((const uint4*)out)[i];
        float4 r;
        r.x = fdec(k.x); r.y = fdec(k.y); r.z = fdec(k.z); r.w = fdec(k.w);
        ((float4*)out)[i] = r;
    }
}

// ---------------- CSR build ----------------
__global__ void hist_kernel(const int* __restrict__ dstI, int* __restrict__ counts, int E) {
    int i = blockIdx.x * blockDim.x + threadIdx.x;
    if (i < E) atomicAdd(&counts[dstI[i]], 1);
}

// exclusive scan of one 1024-chunk per block; optional per-block totals.
__global__ __launch_bounds__(1024) void scan_blk(const int* __restrict__ in,
                                                 int* __restrict__ outp,
                                                 int* __restrict__ bsums, int N) {
    __shared__ int wsum[16];
    const int tid = threadIdx.x, lane = tid & 63, wid = tid >> 6;
    int i = blockIdx.x * 1024 + tid;
    int v = (i < N) ? in[i] : 0;
    int incl = v;
#pragma unroll
    for (int m = 1; m < 64; m <<= 1) {
        int t = __shfl_up(incl, m, 64);
        if (lane >= m) incl += t;
    }
    if (lane == 63) wsum[wid] = incl;
    __syncthreads();
    int woff = 0;
#pragma unroll
    for (int k = 0; k < 16; ++k) woff += (k < wid) ? wsum[k] : 0;
    if (i < N) outp[i] = woff + incl - v;
    if (tid == 1023 && bsums != nullptr) bsums[blockIdx.x] = woff + incl;
}

// scatter with fused top-level offset (bsums already scanned).
__global__ void scatter_kernel(const int* __restrict__ srcI, const int* __restrict__ dstI,
                               int* __restrict__ nextp, const int* __restrict__ bsums,
                               int2* __restrict__ se, int* __restrict__ dst_g, int E) {
    int i = blockIdx.x * blockDim.x + threadIdx.x;
    if (i < E) {
        int d = dstI[i];
        int p = bsums[d >> 10] + atomicAdd(&nextp[d], 1);
        se[p] = make_int2(srcI[i], i);
        dst_g[p] = d;
    }
}

// ---------------- CSR edge kernel: 8 waves/block, cross-tile prefetch ------
__global__ __launch_bounds__(512, 4) void edge_kernel_csr(
    const float* __restrict__ x,   const float* __restrict__ pos,
    const float* __restrict__ nrm, const float* __restrict__ ea,
    const float* __restrict__ W1,  const float* __restrict__ b1,
    const float* __restrict__ g1,  const float* __restrict__ be1,
    const float* __restrict__ W2,  const float* __restrict__ b2,
    const float* __restrict__ g2,  const float* __restrict__ be2,
    const int2* __restrict__ se,   const int* __restrict__ dst_g,
    unsigned* __restrict__ out, int E, int ntiles, int tilesPerBlock)
{
    __shared__ _Float16 W1t[48][LDK];     // 6.0 KB  (swizzled [n][k])
    __shared__ _Float16 W2t[128][LDK];    // 16.0 KB
    __shared__ _Float16 msgA[128][LDK];   // 16.0 KB (msg; h1 aliased after GEMM1)
    __shared__ _Float16 h2w[128][LDH];    // 33.0 KB (linear; walk is 2-way = free)
    __shared__ int dstL[128];

    const int lane = threadIdx.x & 63;
    const int w    = threadIdx.x >> 6;   // 0..7
    const int c16  = lane & 15;
    const int g    = lane >> 4;
    const int row0 = w * 16;

    // ---- stage weights (f16, transposed, zero-padded, swizzled) ----
    for (int i = threadIdx.x; i < 48 * 64; i += 512) {
        int n = i >> 6, k = i & 63;
        W1t[n][swz(n, k)] = (n < 47 && k < 47) ? (_Float16)W1[k * 47 + n] : (_Float16)0.f;
    }
    for (int i = threadIdx.x; i < 128 * 64; i += 512) {
        int n = i >> 6, k = i & 63;
        W2t[n][swz(n, k)] = (k < 47) ? (_Float16)W2[k * 128 + n] : (_Float16)0.f;
    }
    for (int i = threadIdx.x; i < 128 * LDK; i += 512)
        (&msgA[0][0])[i] = (_Float16)0.f;

    // ---- per-lane LN params ----
    float b1v[3], g1v[3], be1v[3];
#pragma unroll
    for (int n = 0; n < 3; ++n) {
        int cc = n * 16 + c16;
        bool vld = cc < 47;
        b1v[n]  = vld ? b1[cc]  : 0.f;
        g1v[n]  = vld ? g1[cc]  : 0.f;
        be1v[n] = vld ? be1[cc] : 0.f;
    }
    float b2v[8];
    f16x2 g2pk[4], be2pk[4];   // packed pairs: channels (2h)*16+c16, (2h+1)*16+c16
#pragma unroll
    for (int n = 0; n < 8; ++n) b2v[n] = b2[n * 16 + c16];
#pragma unroll
    for (int h = 0; h < 4; ++h) {
        g2pk[h][0]  = (_Float16)g2[(2 * h) * 16 + c16];
        g2pk[h][1]  = (_Float16)g2[(2 * h + 1) * 16 + c16];
        be2pk[h][0] = (_Float16)be2[(2 * h) * 16 + c16];
        be2pk[h][1] = (_Float16)be2[(2 * h + 1) * 16 + c16];
    }
    __syncthreads();

    // gather lane roles
    const int xr = lane >> 2;            // x: row within wave's 16 edges
    const int xc = (lane & 3) * 8;       //    8 channels per lane
    const int eg = lane / 11, ec = lane - eg * 11;   // ea: lanes<44
    const bool ea_act  = lane < 44;
    const bool geo_act = lane < 48;

    const int tbeg = blockIdx.x * tilesPerBlock;
    int tend = tbeg + tilesPerBlock;
    if (tend > ntiles) tend = ntiles;
    if (tbeg >= tend) return;

    // ---- cross-tile prefetch state: NAMED SCALARS ONLY (r5 lesson) ----
    int   pf_sx = 0;                     // se[base+xr].x          (x role)
    int   pf_e0 = -1, pf_e1 = -1, pf_e2 = -1, pf_e3 = -1;   // se[..].y (ea role)
    int   pf_gs = 0,  pf_gd = -1;        // se[pg].x, dst_g[pg]    (geo role)
    float pf_ea0 = 0.f, pf_ea1 = 0.f, pf_ea2 = 0.f, pf_ea3 = 0.f;

    // prologue: level-1 indices + ea values for the first tile
    {
        const int b2 = tbeg * 128 + row0;
        int p = b2 + xr;
        pf_sx = (p < E) ? se[p].x : 0;
        if (ea_act) {
            int p0 = b2 + eg, p1 = b2 + 4 + eg, p2 = b2 + 8 + eg, p3 = b2 + 12 + eg;
            pf_e0 = (p0 < E) ? se[p0].y : -1;
            pf_e1 = (p1 < E) ? se[p1].y : -1;
            pf_e2 = (p2 < E) ? se[p2].y : -1;
            pf_e3 = (p3 < E) ? se[p3].y : -1;
            pf_ea0 = (pf_e0 >= 0) ? ea[(size_t)pf_e0 * 11 + ec] : 0.f;
            pf_ea1 = (pf_e1 >= 0) ? ea[(size_t)pf_e1 * 11 + ec] : 0.f;
            pf_ea2 = (pf_e2 >= 0) ? ea[(size_t)pf_e2 * 11 + ec] : 0.f;
            pf_ea3 = (pf_e3 >= 0) ? ea[(size_t)pf_e3 * 11 + ec] : 0.f;
        }
        if (geo_act) {
            int pg = b2 + c16;
            bool v = pg < E;
            pf_gs = v ? se[pg].x : 0;
            pf_gd = v ? dst_g[pg] : -1;
        }
    }

    for (int tile = tbeg; tile < tend; ++tile) {
        const int base = tile * 128 + row0;   // this wave's 16 CSR positions
        const bool more = (tile + 1 < tend);

        // consume prefetched state for THIS tile
        const int   c_sx  = pf_sx;
        const int   c_gs  = pf_gs;
        const int   c_gd  = pf_gd;
        const float cea0 = pf_ea0, cea1 = pf_ea1, cea2 = pf_ea2, cea3 = pf_ea3;

        // issue level-1 prefetch for tile+1 (hidden under this whole window)
        if (more) {
            const int b2 = base + 128;
            int p = b2 + xr;
            pf_sx = (p < E) ? se[p].x : 0;
            if (ea_act) {
                int p0 = b2 + eg, p1 = b2 + 4 + eg, p2 = b2 + 8 + eg, p3 = b2 + 12 + eg;
                pf_e0 = (p0 < E) ? se[p0].y : -1;
                pf_e1 = (p1 < E) ? se[p1].y : -1;
                pf_e2 = (p2 < E) ? se[p2].y : -1;
                pf_e3 = (p3 < E) ? se[p3].y : -1;
            }
            if (geo_act) {
                int pg = b2 + c16;
                bool v = pg < E;
                pf_gs = v ? se[pg].x : 0;
                pf_gd = v ? dst_g[pg] : -1;
            }
        }

        // ---- Phase 1: second-level gathers (x, pos, nrm) + commit ----
        {
            int p = base + xr;
            bool vx = p < E;
            const float4* xp = (const float4*)(x + (size_t)c_sx * 32 + xc);
            float4 xa = xp[0];
            float4 xb = xp[1];

            float gpix = 0.f, gpiy = 0.f, gpiz = 0.f;
            float gpjx = 0.f, gpjy = 0.f, gpjz = 0.f;
            float gnix = 0.f, gniy = 0.f, gniz = 0.f;
            float gnjx = 0.f, gnjy = 0.f, gnjz = 0.f;
            if (geo_act) {
                int d2 = (c_gd < 0) ? 0 : c_gd;
                gpix = pos[d2 * 3 + 0]; gpiy = pos[d2 * 3 + 1]; gpiz = pos[d2 * 3 + 2];
                gpjx = pos[c_gs * 3 + 0]; gpjy = pos[c_gs * 3 + 1]; gpjz = pos[c_gs * 3 + 2];
                gnix = nrm[d2 * 3 + 0]; gniy = nrm[d2 * 3 + 1]; gniz = nrm[d2 * 3 + 2];
                gnjx = nrm[c_gs * 3 + 0]; gnjy = nrm[c_gs * 3 + 1]; gnjz = nrm[c_gs * 3 + 2];
            }

            // commit x
            {
                int r = row0 + xr;
                f16x8 hv;
                hv[0] = (_Float16)(vx ? xa.x : 0.f); hv[1] = (_Float16)(vx ? xa.y : 0.f);
                hv[2] = (_Float16)(vx ? xa.z : 0.f); hv[3] = (_Float16)(vx ? xa.w : 0.f);
                hv[4] = (_Float16)(vx ? xb.x : 0.f); hv[5] = (_Float16)(vx ? xb.y : 0.f);
                hv[6] = (_Float16)(vx ? xb.z : 0.f); hv[7] = (_Float16)(vx ? xb.w : 0.f);
                *(f16x8*)&msgA[r][swz(r, xc)] = hv;
            }
            // commit ea (values prefetched last iteration; invalid already 0)
            if (ea_act) {
                int r0 = row0 + 0 * 4 + eg; msgA[r0][swz(r0, 36 + ec)] = (_Float16)cea0;
                int r1 = row0 + 1 * 4 + eg; msgA[r1][swz(r1, 36 + ec)] = (_Float16)cea1;
                int r2 = row0 + 2 * 4 + eg; msgA[r2][swz(r2, 36 + ec)] = (_Float16)cea2;
                int r3 = row0 + 3 * 4 + eg; msgA[r3][swz(r3, 36 + ec)] = (_Float16)cea3;
            }
            // commit geometry (angle g per lane group)
            if (geo_act) {
                int r = row0 + c16;
                float px = gpjx - gpix, py = gpjy - gpiy, pz = gpjz - gpiz;
                float v1x, v1y, v1z, v2x, v2y, v2z;
                if (g == 0)      { v1x = gnix; v1y = gniy; v1z = gniz; v2x = px;   v2y = py;   v2z = pz; }
                else if (g == 1) { v1x = gnjx; v1y = gnjy; v1z = gnjz; v2x = px;   v2y = py;   v2z = pz; }
                else             { v1x = gnix; v1y = gniy; v1z = gniz; v2x = gnjx; v2y = gnjy; v2z = gnjz; }
                float cx = v1y * v2z - v1z * v2y;
                float cy = v1z * v2x - v1x * v2z;
                float cz = v1x * v2y - v1y * v2x;
                float ang = atan2f(sqrtf(cx * cx + cy * cy + cz * cz),
                                   v1x * v2x + v1y * v2y + v1z * v2z);
                msgA[r][swz(r, 33 + g)] = (_Float16)ang;
                if (g == 0) {
                    msgA[r][swz(r, 32)] = (_Float16)sqrtf(px * px + py * py + pz * pz);
                    dstL[r] = c_gd;
                }
            }
        }
        // no barrier: all LDS rows above are wave-private

        // ---- Phase 2: GEMM1 (16x48) + LN1 -> h1 back into msgA ----
        f32x4 acc1[3];
#pragma unroll
        for (int n = 0; n < 3; ++n) acc1[n] = (f32x4){0.f, 0.f, 0.f, 0.f};
#pragma unroll
        for (int ks = 0; ks < 2; ++ks) {
            int ar = row0 + c16;
            f16x8 a = *(const f16x8*)&msgA[ar][swz(ar, ks * 32 + g * 8)];
#pragma unroll
            for (int n = 0; n < 3; ++n) {
                int br = n * 16 + c16;
                f16x8 b = *(const f16x8*)&W1t[br][swz(br, ks * 32 + g * 8)];
                acc1[n] = __builtin_amdgcn_mfma_f32_16x16x32_f16(a, b, acc1[n], 0, 0, 0);
            }
        }
#pragma unroll
        for (int q = 0; q < 4; ++q) {
            float t0 = fmaxf(acc1[0][q] + b1v[0], 0.f);
            float t1 = fmaxf(acc1[1][q] + b1v[1], 0.f);
            float t2 = fmaxf(acc1[2][q] + b1v[2], 0.f);   // col 47 -> 0
            float s = t0 + t1 + t2;
            float s2 = t0 * t0 + t1 * t1 + t2 * t2;
#pragma unroll
            for (int m = 1; m < 16; m <<= 1) {
                s  += __shfl_xor(s,  m, 64);
                s2 += __shfl_xor(s2, m, 64);
            }
            float mu  = s * (1.f / 47.f);
            float var = s2 * (1.f / 47.f) - mu * mu;
            float rs  = rsqrtf(var + 1e-5f);
            int r = row0 + 4 * g + q;
            msgA[r][swz(r, c16)]      = (_Float16)((t0 - mu) * rs * g1v[0] + be1v[0]);
            msgA[r][swz(r, 16 + c16)] = (_Float16)((t1 - mu) * rs * g1v[1] + be1v[1]);
            msgA[r][swz(r, 32 + c16)] = (_Float16)((t2 - mu) * rs * g1v[2] + be1v[2]);
        }

        // issue level-2 ea prefetch for tile+1 (level-1 loads returned by now;
        // hidden under GEMM2 + LN2 + walk)
        if (more && ea_act) {
            pf_ea0 = (pf_e0 >= 0) ? ea[(size_t)pf_e0 * 11 + ec] : 0.f;
            pf_ea1 = (pf_e1 >= 0) ? ea[(size_t)pf_e1 * 11 + ec] : 0.f;
            pf_ea2 = (pf_e2 >= 0) ? ea[(size_t)pf_e2 * 11 + ec] : 0.f;
            pf_ea3 = (pf_e3 >= 0) ? ea[(size_t)pf_e3 * 11 + ec] : 0.f;
        }

        // ---- Phase 3: GEMM2 (16x128) + LN2 (packed-f16 apply) -> h2w ----
        f32x4 acc2[8];
#pragma unroll
        for (int n = 0; n < 8; ++n) acc2[n] = (f32x4){0.f, 0.f, 0.f, 0.f};
#pragma unroll
        for (int ks = 0; ks < 2; ++ks) {
            int ar = row0 + c16;
            f16x8 a = *(const f16x8*)&msgA[ar][swz(ar, ks * 32 + g * 8)];
#pragma unroll
            for (int n = 0; n < 8; ++n) {
                int br = n * 16 + c16;
                f16x8 b = *(const f16x8*)&W2t[br][swz(br, ks * 32 + g * 8)];
                acc2[n] = __builtin_amdgcn_mfma_f32_16x16x32_f16(a, b, acc2[n], 0, 0, 0);
            }
        }
#pragma unroll
        for (int q = 0; q < 4; ++q) {
            float t[8];
            float s = 0.f, s2 = 0.f;
#pragma unroll
            for (int n = 0; n < 8; ++n) {
                t[n] = fmaxf(acc2[n][q] + b2v[n], 0.f);
                s += t[n]; s2 += t[n] * t[n];
            }
#pragma unroll
            for (int m = 1; m < 16; m <<= 1) {
                s  += __shfl_xor(s,  m, 64);
                s2 += __shfl_xor(s2, m, 64);
            }
            float mu  = s * (1.f / 128.f);
            float var = s2 * (1.f / 128.f) - mu * mu;
            float rs  = rsqrtf(var + 1e-5f);
            int r = row0 + 4 * g + q;
            // packed apply: h = (t*rs - mu*rs)*gamma + beta, two v_pk_fma_f16
            f16x2 apk = pkrtz(rs, rs);
            f16x2 cpk = pkrtz(-mu * rs, -mu * rs);
#pragma unroll
            for (int h = 0; h < 4; ++h) {
                f16x2 tpk = pkrtz(t[2 * h], t[2 * h + 1]);
                f16x2 z   = tpk * apk + cpk;
                f16x2 hvp = z * g2pk[h] + be2pk[h];
                h2w[r][(2 * h) * 16 + c16]     = hvp[0];
                h2w[r][(2 * h + 1) * 16 + c16] = hvp[1];
            }
        }

        // ---- Phase 4: segmented max walk (f16 max; decode at emit only) ----
        {
            f16x2 mneg; mneg[0] = mneg[1] = (_Float16)(-65504.f);
            f16x2 mx = mneg;
            int segStart = 0;
            int dcur = dstL[row0];
#pragma unroll
            for (int r = 0; r < 16; ++r) {
                f16x2 pk = *(const f16x2*)&h2w[row0 + r][lane * 2];
                mx[0] = (pk[0] > mx[0]) ? pk[0] : mx[0];
                mx[1] = (pk[1] > mx[1]) ? pk[1] : mx[1];
                int dnext = (r < 15) ? dstL[row0 + r + 1] : -2;
                if (dnext != dcur) {
                    if (dcur >= 0) {
                        unsigned e0 = fenc((float)mx[0]);
                        unsigned e1 = fenc((float)mx[1]);
                        unsigned* orow = out + (size_t)dcur * 128 + lane * 2;
                        if (segStart > 0 && r < 15) {
                            unsigned long long pk2 =
                                ((unsigned long long)e1 << 32) | (unsigned long long)e0;
                            *(unsigned long long*)orow = pk2;
                        } else {
                            atomicMax(orow,     e0);
                            atomicMax(orow + 1, e1);
                        }
                    }
                    mx = mneg;
                    segStart = r + 1; dcur = dnext;
                }
            }
        }
    }
}

// ---------------- fallback: direct atomics, no CSR (round-2 form) ----------------
#define LDKF 72
__global__ __launch_bounds__(256) void edge_kernel_atomic(
    const float* __restrict__ x,   const float* __restrict__ pos,
    const float* __restrict__ nrm, const float* __restrict__ ea,
    const float* __restrict__ W1,  const float* __restrict__ b1,
    const float* __restrict__ g1,  const float* __restrict__ be1,
    const float* __restrict__ W2,  const float* __restrict__ b2,
    const float* __restrict__ g2,  const float* __restrict__ be2,
    const int* __restrict__ srcI,  const int* __restrict__ dstI,
    unsigned* __restrict__ out, int E, int ntiles)
{
    __shared__ _Float16 W1t[48][LDKF];
    __shared__ _Float16 W2t[128][LDKF];
    __shared__ _Float16 msgA[64][LDKF];
    __shared__ int dst_s[64];

    const int lane = threadIdx.x & 63;
    const int w    = threadIdx.x >> 6;
    const int c16  = lane & 15;
    const int g    = lane >> 4;

    for (int i = threadIdx.x; i < 48 * 64; i += 256) {
        int n = i >> 6, k = i & 63;
        W1t[n][k] = (n < 47 && k < 47) ? (_Float16)W1[k * 47 + n] : (_Float16)0.f;
    }
    for (int i = threadIdx.x; i < 128 * 64; i += 256) {
        int n = i >> 6, k = i & 63;
        W2t[n][k] = (k < 47) ? (_Float16)W2[k * 128 + n] : (_Float16)0.f;
    }
    for (int i = threadIdx.x; i < 64 * LDKF; i += 256)
        (&msgA[0][0])[i] = (_Float16)0.f;

    float b1v[3], g1v[3], be1v[3];
#pragma unroll
    for (int n = 0; n < 3; ++n) {
        int cc = n * 16 + c16;
        bool vld = cc < 47;
        b1v[n]  = vld ? b1[cc]  : 0.f;
        g1v[n]  = vld ? g1[cc]  : 0.f;
        be1v[n] = vld ? be1[cc] : 0.f;
    }
    float b2v[8], g2v[8], be2v[8];
#pragma unroll
    for (int n = 0; n < 8; ++n) {
        int cc = n * 16 + c16;
        b2v[n] = b2[cc]; g2v[n] = g2[cc]; be2v[n] = be2[cc];
    }
    __syncthreads();

    for (int tile = blockIdx.x; tile < ntiles; tile += gridDim.x) {
        const int base = tile * 64 + w * 16;
        const int row0 = w * 16;
#pragma unroll
        for (int i = 0; i < 8; ++i) {
            int el = i * 2 + (lane >> 5);
            int e  = base + el;
            int c  = lane & 31;
            float v = 0.f;
            if (e < E) v = x[(size_t)srcI[e] * 32 + c];
            msgA[row0 + el][c] = (_Float16)v;
        }
        if (lane < 44) {
            int eg = lane / 11, c = lane - eg * 11;
#pragma unroll
            for (int i = 0; i < 4; ++i) {
                int el = i * 4 + eg;
                int e  = base + el;
                float v = 0.f;
                if (e < E) v = ea[(size_t)e * 11 + c];
                msgA[row0 + el][36 + c] = (_Float16)v;
            }
        }
        if (lane < 48) {
            int el = c16;
            int e  = base + el;
            int s = 0, d = 0;
            bool vld = e < E;
            if (vld) { s = srcI[e]; d = dstI[e]; }
            float pix = pos[d * 3 + 0], piy = pos[d * 3 + 1], piz = pos[d * 3 + 2];
            float pjx = pos[s * 3 + 0], pjy = pos[s * 3 + 1], pjz = pos[s * 3 + 2];
            float nix = nrm[d * 3 + 0], niy = nrm[d * 3 + 1], niz = nrm[d * 3 + 2];
            float njx = nrm[s * 3 + 0], njy = nrm[s * 3 + 1], njz = nrm[s * 3 + 2];
            float px = pjx - pix, py = pjy - piy, pz = pjz - piz;
            float v1x, v1y, v1z, v2x, v2y, v2z;
            if (g == 0)      { v1x = nix; v1y = niy; v1z = niz; v2x = px;  v2y = py;  v2z = pz;  }
            else if (g == 1) { v1x = njx; v1y = njy; v1z = njz; v2x = px;  v2y = py;  v2z = pz;  }
            else             { v1x = nix; v1y = niy; v1z = niz; v2x = njx; v2y = njy; v2z = njz; }
            float cx = v1y * v2z - v1z * v2y;
            float cy = v1z * v2x - v1x * v2z;
            float cz = v1x * v2y - v1y * v2x;
            float ang = atan2f(sqrtf(cx * cx + cy * cy + cz * cz),
                               v1x * v2x + v1y * v2y + v1z * v2z);
            msgA[row0 + el][33 + g] = (_Float16)ang;
            if (g == 0) {
                msgA[row0 + el][32] = (_Float16)sqrtf(px * px + py * py + pz * pz);
                dst_s[row0 + el] = vld ? d : -1;
            }
        }

        f32x4 acc1[3];
#pragma unroll
        for (int n = 0; n < 3; ++n) acc1[n] = (f32x4){0.f, 0.f, 0.f, 0.f};
#pragma unroll
        for (int ks = 0; ks < 2; ++ks) {
            f16x8 a = *(const f16x8*)&msgA[row0 + c16][ks * 32 + g * 8];
#pragma unroll
            for (int n = 0; n < 3; ++n) {
                f16x8 b = *(const f16x8*)&W1t[n * 16 + c16][ks * 32 + g * 8];
                acc1[n] = __builtin_amdgcn_mfma_f32_16x16x32_f16(a, b, acc1[n], 0, 0, 0);
            }
        }
#pragma unroll
        for (int q = 0; q < 4; ++q) {
            float t0 = fmaxf(acc1[0][q] + b1v[0], 0.f);
            float t1 = fmaxf(acc1[1][q] + b1v[1], 0.f);
            float t2 = fmaxf(acc1[2][q] + b1v[2], 0.f);
            float s = t0 + t1 + t2;
            float s2 = t0 * t0 + t1 * t1 + t2 * t2;
#pragma unroll
            for (int m = 1; m < 16; m <<= 1) {
                s  += __shfl_xor(s,  m, 64);
                s2 += __shfl_xor(s2, m, 64);
            }
            float mu  = s * (1.f / 47.f);
            float var = s2 * (1.f / 47.f) - mu * mu;
            float rs  = rsqrtf(var + 1e-5f);
            int r = row0 + 4 * g + q;
            msgA[r][c16]      = (_Float16)((t0 - mu) * rs * g1v[0] + be1v[0]);
            msgA[r][16 + c16] = (_Float16)((t1 - mu) * rs * g1v[1] + be1v[1]);
            msgA[r][32 + c16] = (_Float16)((t2 - mu) * rs * g1v[2] + be1v[2]);
        }

        f32x4 acc2[8];
#pragma unroll
        for (int n = 0; n < 8; ++n) acc2[n] = (f32x4){0.f, 0.f, 0.f, 0.f};
#pragma unroll
        for (int ks = 0; ks < 2; ++ks) {
            f16x8 a = *(const f16x8*)&msgA[row0 + c16][ks * 32 + g * 8];
#pragma unroll
            for (int n = 0; n < 8; ++n) {
                f16x8 b = *(const f16x8*)&W2t[n * 16 + c16][ks * 32 + g * 8];
                acc2[n] = __builtin_amdgcn_mfma_f32_16x16x32_f16(a, b, acc2[n], 0, 0, 0);
            }
        }
        int4 dd = *(const int4*)&dst_s[row0 + 4 * g];
#pragma unroll
        for (int q = 0; q < 4; ++q) {
            float t[8];
            float s = 0.f, s2 = 0.f;
#pragma unroll
            for (int n = 0; n < 8; ++n) {
                t[n] = fmaxf(acc2[n][q] + b2v[n], 0.f);
                s += t[n]; s2 += t[n] * t[n];
            }
#pragma unroll
            for (int m = 1; m < 16; m <<= 1) {
                s  += __shfl_xor(s,  m, 64);
                s2 += __shfl_xor(s2, m, 64);
            }
            float mu  = s * (1.f / 128.f);
            float var = s2 * (1.f / 128.f) - mu * mu;
            float rs  = rsqrtf(var + 1e-5f);
            int d = (&dd.x)[q];
            if (d >= 0) {
                unsigned* orow = out + (size_t)d * 128u;
#pragma unroll
                for (int n = 0; n < 8; ++n) {
                    float o = (t[n] - mu) * rs * g2v[n] + be2v[n];
                    atomicMax(orow + n * 16 + c16, fenc(o));
                }
            }
        }
    }
}

extern "C" void kernel_launch(void* const* d_in, const int* in_sizes, int n_in,
                              void* d_out, int out_size, void* d_ws, size_t ws_size,
                              hipStream_t stream) {
    const float* x   = (const float*)d_in[0];
    const float* pos = (const float*)d_in[1];
    const float* nrm = (const float*)d_in[2];
    const float* ea  = (const float*)d_in[3];
    const float* W1  = (const float*)d_in[4];
    const float* b1  = (const float*)d_in[5];
    const float* g1  = (const float*)d_in[6];
    const float* be1 = (const float*)d_in[7];
    const float* W2  = (const float*)d_in[8];
    const float* b2  = (const float*)d_in[9];
    const float* g2  = (const float*)d_in[10];
    const float* be2 = (const float*)d_in[11];
    const int*   idx = (const int*)d_in[12];

    const int N = in_sizes[0] / 32;
    const int E = in_sizes[3] / 11;
    const int* srcI = idx;
    const int* dstI = idx + E;

    unsigned* outU = (unsigned*)d_out;
    const int n = N * 128;

    init_out_kernel<<<(n / 4 + 255) / 256, 256, 0, stream>>>(outU, n / 4);

    const int nb = (N + 1023) / 1024;
    // ws layout: se[E] int2 | counts[N] | nextp[N] | dst_g[E] | bsums[nb]
    const size_t needed = (size_t)E * 8 + (size_t)(2LL * N + E + nb) * 4;

    if (ws_size >= needed) {
        int2* se     = (int2*)d_ws;
        int*  counts = (int*)(se + E);
        int*  nextp  = counts + N;
        int*  dst_g  = nextp + N;
        int*  bsums  = dst_g + E;

        hipMemsetAsync(counts, 0, (size_t)N * 4, stream);
        hist_kernel<<<(E + 255) / 256, 256, 0, stream>>>(dstI, counts, E);
        scan_blk<<<nb, 1024, 0, stream>>>(counts, nextp, bsums, N);
        scan_blk<<<1, 1024, 0, stream>>>(bsums, bsums, (int*)nullptr, nb);
        scatter_kernel<<<(E + 255) / 256, 256, 0, stream>>>(srcI, dstI, nextp, bsums,
                                                            se, dst_g, E);

        const int ntiles = (E + 127) / 128;
        int grid = ntiles < 512 ? ntiles : 512;    // 2 blocks/CU resident, persistent
        int tpb  = (ntiles + grid - 1) / grid;
        edge_kernel_csr<<<grid, 512, 0, stream>>>(x, pos, nrm, ea,
                                                  W1, b1, g1, be1,
                                                  W2, b2, g2, be2,
                                                  se, dst_g,
                                                  outU, E, ntiles, tpb);
    } else {
        const int ntiles = (E + 63) / 64;
        int grid = ntiles < 4096 ? ntiles : 4096;
        edge_kernel_atomic<<<grid, 256, 0, stream>>>(x, pos, nrm, ea,
                                                     W1, b1, g1, be1,
                                                     W2, b2, g2, be2,
                                                     srcI, dstI, outU, E, ntiles);
    }

    finalize_out_kernel<<<(n / 4 + 255) / 256, 256, 0, stream>>>((float*)d_out, n / 4);
}